// Round 1
// baseline (2924.718 us; speedup 1.0000x reference)
//
#include <hip/hip_runtime.h>
#include <math.h>

// Problem constants (fixed by setup_inputs)
#define NB 128
#define NI 2048
#define NU 16
#define NJ 32
#define NV 16
#define NJV 512   // NJ*NV

// One wave handles one (b,i) pair per loop iteration.
// Lane L owns jv slots {L + 64k : k=0..7}; j = 4k + (L>>4), v = L&15.
// MODE==0: first routing iter, c uniform = 1/32 (softmax of zeros).
// MODE==1: logits = dot(u[b,i,j,:], Vacc[b,j,:]), softmax over j, weighted accum.
template<int MODE>
__global__ __launch_bounds__(256, 4)
void pass_kernel(const float* __restrict__ x, const float* __restrict__ W,
                 const float* __restrict__ Vacc, float* __restrict__ s_out)
{
    __shared__ float s_lds[4][NJV];
    const int lane = threadIdx.x & 63;
    const int wave = threadIdx.x >> 6;
    const int b    = blockIdx.y;
    const int i0   = blockIdx.x * 128 + wave * 32;   // 32 i's per wave

    float vacc[8];
    if (MODE) {
#pragma unroll
        for (int k = 0; k < 8; ++k)
            vacc[k] = Vacc[b * NJV + lane + 64 * k];
    }

    float s_local[8];
#pragma unroll
    for (int k = 0; k < 8; ++k) s_local[k] = 0.f;

    for (int t = 0; t < 32; ++t) {
        const int i = i0 + t;

        // x[b,i,0..15] — wave-uniform address, broadcast load
        const float* xp = x + ((size_t)b * NI + i) * NU;
        float xr[16];
#pragma unroll
        for (int q = 0; q < 4; ++q) {
            float4 x4 = *(const float4*)(xp + 4 * q);
            xr[4*q+0] = x4.x; xr[4*q+1] = x4.y; xr[4*q+2] = x4.z; xr[4*q+3] = x4.w;
        }

        // votes: u[k] = sum_u x[b,i,u] * W[i, jv(k), u]
        const float* Wp = W + (size_t)i * (NJV * NU);
        float uv[8];
#pragma unroll
        for (int k = 0; k < 8; ++k) {
            const float* wp = Wp + (size_t)(lane + 64 * k) * NU;
            float4 w0 = *(const float4*)(wp + 0);
            float4 w1 = *(const float4*)(wp + 4);
            float4 w2 = *(const float4*)(wp + 8);
            float4 w3 = *(const float4*)(wp + 12);
            float acc = xr[0] * w0.x;
            acc = fmaf(xr[1],  w0.y, acc);
            acc = fmaf(xr[2],  w0.z, acc);
            acc = fmaf(xr[3],  w0.w, acc);
            acc = fmaf(xr[4],  w1.x, acc);
            acc = fmaf(xr[5],  w1.y, acc);
            acc = fmaf(xr[6],  w1.z, acc);
            acc = fmaf(xr[7],  w1.w, acc);
            acc = fmaf(xr[8],  w2.x, acc);
            acc = fmaf(xr[9],  w2.y, acc);
            acc = fmaf(xr[10], w2.z, acc);
            acc = fmaf(xr[11], w2.w, acc);
            acc = fmaf(xr[12], w3.x, acc);
            acc = fmaf(xr[13], w3.y, acc);
            acc = fmaf(xr[14], w3.z, acc);
            acc = fmaf(xr[15], w3.w, acc);
            uv[k] = acc;
        }

        float c[8];
        if (MODE == 0) {
#pragma unroll
            for (int k = 0; k < 8; ++k) c[k] = (1.0f / 32.0f);
        } else {
            // logits[j] = sum_v u[j,v] * Vacc[j,v]: reduce over the 16-lane v-group
            float lg[8];
#pragma unroll
            for (int k = 0; k < 8; ++k) lg[k] = uv[k] * vacc[k];
#pragma unroll
            for (int m = 1; m < 16; m <<= 1) {
#pragma unroll
                for (int k = 0; k < 8; ++k)
                    lg[k] += __shfl_xor(lg[k], m, 64);
            }
            // softmax over all 32 j's: per-lane 8 logits (j = 4k+g), combine 4 groups
            float mx = lg[0];
#pragma unroll
            for (int k = 1; k < 8; ++k) mx = fmaxf(mx, lg[k]);
            mx = fmaxf(mx, __shfl_xor(mx, 16, 64));
            mx = fmaxf(mx, __shfl_xor(mx, 32, 64));
            float sum = 0.f;
#pragma unroll
            for (int k = 0; k < 8; ++k) { c[k] = __expf(lg[k] - mx); sum += c[k]; }
            sum += __shfl_xor(sum, 16, 64);
            sum += __shfl_xor(sum, 32, 64);
            float inv = __builtin_amdgcn_rcpf(sum);
#pragma unroll
            for (int k = 0; k < 8; ++k) c[k] *= inv;
        }

#pragma unroll
        for (int k = 0; k < 8; ++k) s_local[k] = fmaf(c[k], uv[k], s_local[k]);
    }

    // combine 4 waves' partials in LDS, then one atomicAdd per slot
#pragma unroll
    for (int k = 0; k < 8; ++k) s_lds[wave][lane + 64 * k] = s_local[k];
    __syncthreads();
    for (int slot = threadIdx.x; slot < NJV; slot += 256) {
        float v = s_lds[0][slot] + s_lds[1][slot] + s_lds[2][slot] + s_lds[3][slot];
        atomicAdd(&s_out[b * NJV + slot], v);
    }
}

// squash + bias; mode 0: Vacc = v ; mode 1: Vacc += v ; mode 2: out = v
__global__ __launch_bounds__(256)
void squash_kernel(const float* __restrict__ s_in, const float* __restrict__ bias,
                   float* __restrict__ Vacc, float* __restrict__ out, int mode)
{
    int idx = blockIdx.x * 256 + threadIdx.x;    // over NB*NJ*NV = 65536
    float s = s_in[idx] + bias[idx & (NJV - 1)];
    float sq = s * s;
#pragma unroll
    for (int m = 1; m < 16; m <<= 1) sq += __shfl_xor(sq, m, 64);
    float val = s * sq / (1.0f + sq) / sqrtf(sq + 1e-9f);
    if (mode == 0)      Vacc[idx] = val;
    else if (mode == 1) Vacc[idx] += val;
    else                out[idx]  = val;
}

extern "C" void kernel_launch(void* const* d_in, const int* in_sizes, int n_in,
                              void* d_out, int out_size, void* d_ws, size_t ws_size,
                              hipStream_t stream)
{
    const float* x    = (const float*)d_in[0];
    const float* W    = (const float*)d_in[1];
    const float* bias = (const float*)d_in[2];
    float* out = (float*)d_out;

    float* s_buf = (float*)d_ws;             // NB*NJV floats = 256 KB
    float* Vacc  = s_buf + NB * NJV;         // NB*NJV floats = 256 KB

    dim3 grid(16, NB), blk(256);
    dim3 sgrid(NB * NJ * NV / 256), sblk(256);
    size_t s_bytes = (size_t)NB * NJV * sizeof(float);

    // r = 0: uniform coupling
    hipMemsetAsync(s_buf, 0, s_bytes, stream);
    pass_kernel<0><<<grid, blk, 0, stream>>>(x, W, Vacc, s_buf);
    squash_kernel<<<sgrid, sblk, 0, stream>>>(s_buf, bias, Vacc, out, 0); // Vacc = v0

    // r = 1: logits = u . v0
    hipMemsetAsync(s_buf, 0, s_bytes, stream);
    pass_kernel<1><<<grid, blk, 0, stream>>>(x, W, Vacc, s_buf);
    squash_kernel<<<sgrid, sblk, 0, stream>>>(s_buf, bias, Vacc, out, 1); // Vacc += v1

    // r = 2: logits = u . (v0+v1)
    hipMemsetAsync(s_buf, 0, s_bytes, stream);
    pass_kernel<1><<<grid, blk, 0, stream>>>(x, W, Vacc, s_buf);
    squash_kernel<<<sgrid, sblk, 0, stream>>>(s_buf, bias, Vacc, out, 2); // out = v2
}

// Round 2
// 683.643 us; speedup vs baseline: 4.2781x; 4.2781x over previous
//
#include <hip/hip_runtime.h>
#include <math.h>

// Problem constants
#define NB 128
#define NI 2048
#define NU 16
#define NJ 32
#define NV 16
#define NJV 512

// Tiling
#define BI 8           // i's per block
#define IC (NI / BI)   // 256 i-chunks
#define BB 16          // b's per block
#define GB (NB / BB)   // 8 b-groups
#define WB 4           // b's per wave

#define GLD16(g, l) __builtin_amdgcn_global_load_lds( \
    (const __attribute__((address_space(1))) unsigned int*)(g), \
    (__attribute__((address_space(3))) unsigned int*)(l), 16, 0, 0)

__device__ __forceinline__ float rfl(float v) {
    return __uint_as_float(__builtin_amdgcn_readfirstlane(__float_as_uint(v)));
}

// Lane L owns jv slots {L + 64k : k=0..7}; j = 4k + (L>>4), v = L&15.
// Each wave handles WB=4 consecutive b's; W[i] staged in LDS, reused by all waves.
template<int MODE>
__global__ __launch_bounds__(256, 3)
void pass_kernel(const float* __restrict__ x, const float* __restrict__ W,
                 const float* __restrict__ Vacc, float* __restrict__ s_out)
{
    __shared__ float Wbuf[2][4096];          // 2 x 16 KB half-i W tiles
    __shared__ float xbuf[BB * BI * NU];     // 8 KB x tile [b][i][u]

    const int tid   = threadIdx.x;
    const int lane  = tid & 63;
    const int wave  = tid >> 6;
    const int ibase = blockIdx.x * BI;
    const int bblk  = blockIdx.y * BB;
    const int bw    = bblk + wave * WB;      // wave's first b

    // Vacc fragments for this wave's 4 b's (issued before staging so the
    // counted vmcnt(4) below also covers them)
    float vacc[WB][8];
    if (MODE) {
#pragma unroll
        for (int b = 0; b < WB; ++b)
#pragma unroll
            for (int k = 0; k < 8; ++k)
                vacc[b][k] = Vacc[(size_t)(bw + b) * NJV + lane + 64 * k];
    }

    // ---- prologue staging: x tile (2 insts) + W half (0,0) (4 insts) ----
#pragma unroll
    for (int q = 0; q < 2; ++q) {
        int f   = q * 1024 + tid * 4;        // flat float index in xbuf
        int lb  = f >> 7;                    // local b (128 floats per b)
        int rem = f & 127;
        const float* g = x + (size_t)(bblk + lb) * (NI * NU) + ibase * NU + rem;
        GLD16(g, &xbuf[f]);
    }
    {
        const float* g0 = W + (size_t)ibase * (NJV * NU);
#pragma unroll
        for (int q = 0; q < 4; ++q)
            GLD16(g0 + q * 1024 + tid * 4, &Wbuf[0][q * 1024 + tid * 4]);
    }

    float uv[WB][8];
    float s_local[WB][8];
#pragma unroll
    for (int b = 0; b < WB; ++b)
#pragma unroll
        for (int k = 0; k < 8; ++k) s_local[b][k] = 0.f;

    float xs[WB][NU];   // wave-uniform x values (SGPRs via readfirstlane)

    for (int il = 0; il < BI; ++il) {
        // ======== half 0: stage (il, half1) -> Wbuf[1]; compute k=0..3 from Wbuf[0]
        {
            const float* g = W + (size_t)(ibase + il) * (NJV * NU) + 4096;
#pragma unroll
            for (int q = 0; q < 4; ++q)
                GLD16(g + q * 1024 + tid * 4, &Wbuf[1][q * 1024 + tid * 4]);
        }
        asm volatile("s_waitcnt vmcnt(4)" ::: "memory");  // cur half done, next in flight
        __builtin_amdgcn_s_barrier();
        asm volatile("" ::: "memory");

        // x for this il: broadcast LDS reads -> SGPR
#pragma unroll
        for (int b = 0; b < WB; ++b)
#pragma unroll
            for (int q = 0; q < 4; ++q) {
                float4 v = *(const float4*)&xbuf[(wave * WB + b) * (BI * NU) + il * NU + 4 * q];
                xs[b][4*q+0] = rfl(v.x);
                xs[b][4*q+1] = rfl(v.y);
                xs[b][4*q+2] = rfl(v.z);
                xs[b][4*q+3] = rfl(v.w);
            }

        // votes k = 0..3
#pragma unroll
        for (int kk = 0; kk < 4; ++kk) {
            const float* wp = &Wbuf[0][(lane + 64 * kk) * 16];
#pragma unroll
            for (int q = 0; q < 4; ++q) {
                float4 w = *(const float4*)(wp + 4 * q);
#pragma unroll
                for (int b = 0; b < WB; ++b) {
                    float acc = (q == 0) ? xs[b][0] * w.x
                                         : fmaf(xs[b][4*q+0], w.x, uv[b][kk]);
                    acc = fmaf(xs[b][4*q+1], w.y, acc);
                    acc = fmaf(xs[b][4*q+2], w.z, acc);
                    acc = fmaf(xs[b][4*q+3], w.w, acc);
                    uv[b][kk] = acc;
                }
            }
        }
        asm volatile("" ::: "memory");
        __builtin_amdgcn_s_barrier();       // protect Wbuf[0] before next stage
        asm volatile("" ::: "memory");

        // ======== half 1: stage (il+1, half0) -> Wbuf[0]; compute k=4..7 from Wbuf[1]
        if (il < BI - 1) {
            const float* g = W + (size_t)(ibase + il + 1) * (NJV * NU);
#pragma unroll
            for (int q = 0; q < 4; ++q)
                GLD16(g + q * 1024 + tid * 4, &Wbuf[0][q * 1024 + tid * 4]);
            asm volatile("s_waitcnt vmcnt(4)" ::: "memory");
        } else {
            asm volatile("s_waitcnt vmcnt(0)" ::: "memory");
        }
        __builtin_amdgcn_s_barrier();
        asm volatile("" ::: "memory");

        // votes k = 4..7
#pragma unroll
        for (int kk = 0; kk < 4; ++kk) {
            const float* wp = &Wbuf[1][(lane + 64 * kk) * 16];
#pragma unroll
            for (int q = 0; q < 4; ++q) {
                float4 w = *(const float4*)(wp + 4 * q);
#pragma unroll
                for (int b = 0; b < WB; ++b) {
                    float acc = (q == 0) ? xs[b][0] * w.x
                                         : fmaf(xs[b][4*q+0], w.x, uv[b][4 + kk]);
                    acc = fmaf(xs[b][4*q+1], w.y, acc);
                    acc = fmaf(xs[b][4*q+2], w.z, acc);
                    acc = fmaf(xs[b][4*q+3], w.w, acc);
                    uv[b][4 + kk] = acc;
                }
            }
        }

        // routing + s accumulation
        if (MODE == 0) {
#pragma unroll
            for (int b = 0; b < WB; ++b)
#pragma unroll
                for (int k = 0; k < 8; ++k) s_local[b][k] += uv[b][k];
        } else {
#pragma unroll
            for (int b = 0; b < WB; ++b) {
                float lg[8];
#pragma unroll
                for (int k = 0; k < 8; ++k) lg[k] = uv[b][k] * vacc[b][k];
#pragma unroll
                for (int m = 1; m < 16; m <<= 1)
#pragma unroll
                    for (int k = 0; k < 8; ++k) lg[k] += __shfl_xor(lg[k], m, 64);
                float mx = lg[0];
#pragma unroll
                for (int k = 1; k < 8; ++k) mx = fmaxf(mx, lg[k]);
                mx = fmaxf(mx, __shfl_xor(mx, 16, 64));
                mx = fmaxf(mx, __shfl_xor(mx, 32, 64));
                float p[8], sum = 0.f;
#pragma unroll
                for (int k = 0; k < 8; ++k) { p[k] = __expf(lg[k] - mx); sum += p[k]; }
                sum += __shfl_xor(sum, 16, 64);
                sum += __shfl_xor(sum, 32, 64);
                float inv = __builtin_amdgcn_rcpf(sum);
#pragma unroll
                for (int k = 0; k < 8; ++k)
                    s_local[b][k] = fmaf(p[k] * inv, uv[b][k], s_local[b][k]);
            }
        }
        asm volatile("" ::: "memory");
        __builtin_amdgcn_s_barrier();       // protect Wbuf[1] before next il's stage
        asm volatile("" ::: "memory");
    }

    // epilogue: one atomicAdd per (b, slot)
    const float scale = (MODE == 0) ? (1.0f / NJ) : 1.0f;
#pragma unroll
    for (int b = 0; b < WB; ++b)
#pragma unroll
        for (int k = 0; k < 8; ++k)
            atomicAdd(&s_out[(size_t)(bw + b) * NJV + lane + 64 * k],
                      s_local[b][k] * scale);
}

// squash + bias; mode 0: Vacc = v ; mode 1: Vacc += v ; mode 2: out = v
__global__ __launch_bounds__(256)
void squash_kernel(const float* __restrict__ s_in, const float* __restrict__ bias,
                   float* __restrict__ Vacc, float* __restrict__ out, int mode)
{
    int idx = blockIdx.x * 256 + threadIdx.x;    // over NB*NJV = 65536
    float s = s_in[idx] + bias[idx & (NJV - 1)];
    float sq = s * s;
#pragma unroll
    for (int m = 1; m < 16; m <<= 1) sq += __shfl_xor(sq, m, 64);
    float val = s * sq / (1.0f + sq) / sqrtf(sq + 1e-9f);
    if (mode == 0)      Vacc[idx] = val;
    else if (mode == 1) Vacc[idx] += val;
    else                out[idx]  = val;
}

extern "C" void kernel_launch(void* const* d_in, const int* in_sizes, int n_in,
                              void* d_out, int out_size, void* d_ws, size_t ws_size,
                              hipStream_t stream)
{
    const float* x    = (const float*)d_in[0];
    const float* W    = (const float*)d_in[1];
    const float* bias = (const float*)d_in[2];
    float* out = (float*)d_out;

    float* s_buf = (float*)d_ws;             // NB*NJV floats = 256 KB
    float* Vacc  = s_buf + NB * NJV;         // NB*NJV floats = 256 KB

    dim3 grid(IC, GB), blk(256);
    dim3 sgrid(NB * NJV / 256), sblk(256);
    size_t s_bytes = (size_t)NB * NJV * sizeof(float);

    // r = 0: uniform coupling (softmax of zeros)
    hipMemsetAsync(s_buf, 0, s_bytes, stream);
    pass_kernel<0><<<grid, blk, 0, stream>>>(x, W, Vacc, s_buf);
    squash_kernel<<<sgrid, sblk, 0, stream>>>(s_buf, bias, Vacc, out, 0); // Vacc = v0

    // r = 1: logits = u . v0
    hipMemsetAsync(s_buf, 0, s_bytes, stream);
    pass_kernel<1><<<grid, blk, 0, stream>>>(x, W, Vacc, s_buf);
    squash_kernel<<<sgrid, sblk, 0, stream>>>(s_buf, bias, Vacc, out, 1); // Vacc += v1

    // r = 2: logits = u . (v0+v1)
    hipMemsetAsync(s_buf, 0, s_bytes, stream);
    pass_kernel<1><<<grid, blk, 0, stream>>>(x, W, Vacc, s_buf);
    squash_kernel<<<sgrid, sblk, 0, stream>>>(s_buf, bias, Vacc, out, 2); // out = v2
}